// Round 13
// baseline (147.485 us; speedup 1.0000x reference)
//
#include <hip/hip_runtime.h>
#include <cstdint>
#include <cstddef>

#define D 128
#define ALPHA 0.2f

typedef _Float16 half8_t __attribute__((ext_vector_type(8)));
typedef _Float16 v2h __attribute__((ext_vector_type(2)));
typedef __attribute__((ext_vector_type(4))) float f32x4_t;

static __device__ __forceinline__ ushort f2h(float f) {
    _Float16 h = (_Float16)f;
    return *(ushort*)&h;
}

static __device__ __forceinline__ float dot2f(v2h x, v2h y, float c) {
#if __has_builtin(__builtin_amdgcn_fdot2)
    return __builtin_amdgcn_fdot2(x, y, c, false);
#else
    return fmaf((float)x[0], (float)y[0], fmaf((float)x[1], (float)y[1], c));
#endif
}

// ---------------------------------------------------------------------------
// Kernel 0: W [128][128] fp32 -> Wt [n][k] fp16 (transposed), 64 blocks
// ---------------------------------------------------------------------------
__global__ __launch_bounds__(256) void w_prep_kernel(const float* __restrict__ W,
                                                     ushort* __restrict__ Wt) {
    int idx = blockIdx.x * 256 + threadIdx.x;   // 0..16383
    int k = idx >> 7;
    int n = idx & 127;
    Wt[n * 128 + k] = f2h(W[idx]);
}

// ---------------------------------------------------------------------------
// Kernel 1: Hf = fp16(A @ W) via fp16 MFMA; first 196 blocks also zero counts
// ---------------------------------------------------------------------------
__global__ __launch_bounds__(256) void gemm_h_kernel(const float* __restrict__ A,
                                                     const ushort* __restrict__ Wt,
                                                     ushort* __restrict__ Hf,
                                                     int* __restrict__ counts,
                                                     int N) {
    // fused: zero the histogram counters (independent of GEMM work)
    int zi = blockIdx.x * 256 + threadIdx.x;
    if (zi < N) counts[zi] = 0;

    __shared__ ushort Alds[64][136];
    const int tid = threadIdx.x;
    const int r0 = blockIdx.x * 64;

#pragma unroll
    for (int it = 0; it < 8; ++it) {
        int idx = it * 256 + tid;          // 0..2047
        int r = idx >> 5;
        int c4 = (idx & 31) * 4;
        float4 v = make_float4(0.f, 0.f, 0.f, 0.f);
        if (r0 + r < N) v = *(const float4*)(A + (size_t)(r0 + r) * D + c4);
        ushort4 b;
        b.x = f2h(v.x); b.y = f2h(v.y); b.z = f2h(v.z); b.w = f2h(v.w);
        *(ushort4*)&Alds[r][c4] = b;
    }
    __syncthreads();

    const int lane = tid & 63;
    const int w = tid >> 6;
    const int wm = w >> 1;
    const int wn = w & 1;
    const int l15 = lane & 15;
    const int koff = (lane >> 4) * 8;

    f32x4_t acc[2][4];
#pragma unroll
    for (int mt = 0; mt < 2; ++mt)
#pragma unroll
        for (int nt = 0; nt < 4; ++nt) acc[mt][nt] = (f32x4_t){0.f, 0.f, 0.f, 0.f};

    const int arow = wm * 32 + l15;
#pragma unroll
    for (int kk = 0; kk < 4; ++kk) {
        half8_t am0 = *(const half8_t*)&Alds[arow][kk * 32 + koff];
        half8_t am1 = *(const half8_t*)&Alds[arow + 16][kk * 32 + koff];
        half8_t bn[4];
#pragma unroll
        for (int nt = 0; nt < 4; ++nt)
            bn[nt] = *(const half8_t*)(Wt + (size_t)(wn * 64 + nt * 16 + l15) * 128 + kk * 32 + koff);
#pragma unroll
        for (int nt = 0; nt < 4; ++nt) {
            acc[0][nt] = __builtin_amdgcn_mfma_f32_16x16x32_f16(am0, bn[nt], acc[0][nt], 0, 0, 0);
            acc[1][nt] = __builtin_amdgcn_mfma_f32_16x16x32_f16(am1, bn[nt], acc[1][nt], 0, 0, 0);
        }
    }

    const int crow = (lane >> 4) * 4;
#pragma unroll
    for (int mt = 0; mt < 2; ++mt)
#pragma unroll
        for (int nt = 0; nt < 4; ++nt)
#pragma unroll
            for (int r = 0; r < 4; ++r) {
                int row = r0 + wm * 32 + mt * 16 + crow + r;
                if (row < N)
                    Hf[(size_t)row * D + wn * 64 + nt * 16 + l15] = f2h(acc[mt][nt][r]);
            }
}

// ---------------------------------------------------------------------------
// hist(+rank): rank[i] = running index of edge i within its src bucket
// ---------------------------------------------------------------------------
__global__ __launch_bounds__(256) void hist_rank_kernel(const int* __restrict__ src,
                                                        int* __restrict__ counts,
                                                        int* __restrict__ rank, int E) {
    int i = blockIdx.x * 256 + threadIdx.x;
    if (i >= E) return;
    rank[i] = atomicAdd(&counts[src[i]], 1);
}

// ---------------------------------------------------------------------------
// Merged scan: block b computes its offset by directly summing counts[0..b*256)
// then does the in-block exclusive scan. One dispatch, no blocksum round-trip.
// ---------------------------------------------------------------------------
__global__ __launch_bounds__(256) void scan_kernel(const int* __restrict__ counts,
                                                   int* __restrict__ starts, int N) {
    __shared__ int bsum[4];
    __shared__ int wsum[4];
    int tid = threadIdx.x;
    int lane = tid & 63, w = tid >> 6;

    // phase 1: block offset = sum of counts[0 .. blockIdx.x*256)
    int lim = blockIdx.x << 8;
    int x0 = 0;
    for (int i = tid; i < lim; i += 256) x0 += counts[i];
#pragma unroll
    for (int off = 32; off > 0; off >>= 1) x0 += __shfl_down(x0, off);
    if (lane == 0) bsum[w] = x0;
    __syncthreads();
    int blkoff = bsum[0] + bsum[1] + bsum[2] + bsum[3];

    // phase 2: in-block exclusive scan
    int i = (blockIdx.x << 8) + tid;
    int c = (i < N) ? counts[i] : 0;
    int x = c;
#pragma unroll
    for (int off = 1; off < 64; off <<= 1) {
        int y = __shfl_up(x, off);
        if (lane >= off) x += y;
    }
    if (lane == 63) wsum[w] = x;
    __syncthreads();
    int woff = blkoff;
    for (int j = 0; j < w; ++j) woff += wsum[j];
    int pre = woff + x - c;
    if (i < N) {
        starts[i] = pre;
        if (i == N - 1) starts[N] = pre + c;
    }
}

__global__ __launch_bounds__(256) void scatter_kernel(const int* __restrict__ src,
                                                      const int* __restrict__ dst,
                                                      const int* __restrict__ rank,
                                                      const int* __restrict__ starts,
                                                      int* __restrict__ dsts_sorted, int E) {
    int i = blockIdx.x * 256 + threadIdx.x;
    if (i >= E) return;
    int pos = starts[src[i]] + rank[i];
    dsts_sorted[pos] = dst[i];
}

// ---------------------------------------------------------------------------
// Node kernel: 1 block = 1 wave = 1 node; scalar edge loads (SGPR base).
// Main loop processes 32 edges with ALL 32 gathers issued up-front (deep MLP)
// before the two 16-edge compute phases. fp16 packed QK; butterfly multi-
// reduce; readlane e-broadcast; deferred rowsum fold.
// ---------------------------------------------------------------------------
__device__ __forceinline__ void load_chunk16(const ushort* __restrict__ Hf,
                                             const int* __restrict__ dsts_sorted,
                                             int base, int l, uint fu[16]) {
#pragma unroll
    for (int j = 0; j < 16; ++j) {
        int dj = dsts_sorted[base + j];                  // wave-uniform -> s_load
        const ushort* rp = Hf + ((size_t)(uint)dj << 7); // SGPR base
        fu[j] = *(const uint*)(rp + (l << 1));
    }
}

template <bool FULL>
__device__ __forceinline__ void compute_chunk16(const uint fu[16], int cnt, int l,
                                                v2h hs2, v2h av2, v2h alpha2,
                                                float& acc0, float& acc1, float& rsp) {
    float p[16];
#pragma unroll
    for (int j = 0; j < 16; ++j) {
        v2h hv = *(v2h*)&fu[j];
        v2h s = hs2 + hv;                                    // v_pk_add_f16
        s = __builtin_elementwise_max(s, s * alpha2);        // v_pk_mul + v_pk_max
        float pj = dot2f(s, av2, 0.0f);                      // v_dot2_f32_f16
        p[j] = (FULL || j < cnt) ? pj : -1e30f;
    }
    // butterfly multi-reduce: 16 values over 64 lanes
    {
        bool hi = l & 1;
#pragma unroll
        for (int i = 0; i < 8; ++i) {
            float send = hi ? p[i] : p[i + 8];
            float recv = __shfl_xor(send, 1);
            p[i] = (hi ? p[i + 8] : p[i]) + recv;
        }
        hi = l & 2;
#pragma unroll
        for (int i = 0; i < 4; ++i) {
            float send = hi ? p[i] : p[i + 4];
            float recv = __shfl_xor(send, 2);
            p[i] = (hi ? p[i + 4] : p[i]) + recv;
        }
        hi = l & 4;
#pragma unroll
        for (int i = 0; i < 2; ++i) {
            float send = hi ? p[i] : p[i + 2];
            float recv = __shfl_xor(send, 4);
            p[i] = (hi ? p[i + 2] : p[i]) + recv;
        }
        hi = l & 8;
        {
            float send = hi ? p[0] : p[1];
            float recv = __shfl_xor(send, 8);
            p[0] = (hi ? p[1] : p[0]) + recv;
        }
        p[0] += __shfl_xor(p[0], 16);
        p[0] += __shfl_xor(p[0], 32);
    }
    float e = __expf(p[0]);      // lane l: e of edge brev4(l&15), replicated per 16 lanes
    rsp += e;                    // deferred rowsum fold

    const int brev[16] = {0, 8, 4, 12, 2, 10, 6, 14, 1, 9, 5, 13, 3, 11, 7, 15};
#pragma unroll
    for (int j = 0; j < 16; ++j) {
        float ej = __uint_as_float(
            (uint)__builtin_amdgcn_readlane((int)__float_as_uint(e), brev[j]));
        v2h hv = *(v2h*)&fu[j];
        acc0 = fmaf((float)hv[0], ej, acc0);   // v_fma_mix
        acc1 = fmaf((float)hv[1], ej, acc1);   // v_fma_mix
    }
}

__global__ __launch_bounds__(64) void node_kernel(const ushort* __restrict__ Hf,
                                                  const int* __restrict__ starts,
                                                  const int* __restrict__ dsts_sorted,
                                                  const float* __restrict__ a,
                                                  float* __restrict__ out, int N) {
    const int node = blockIdx.x;   // wave-uniform
    const int l = threadIdx.x;     // 0..63

    const int beg = starts[node];
    const int end = starts[node + 1];

    uint hu = *(const uint*)(Hf + ((size_t)node << 7) + (l << 1));
    v2h hs2 = *(v2h*)&hu;
    float2 af = ((const float2*)a)[l];
    v2h av2 = {(_Float16)af.x, (_Float16)af.y};
    const v2h alpha2 = {(_Float16)ALPHA, (_Float16)ALPHA};

    float acc0 = 0.f, acc1 = 0.f, rsp = 0.f;

    int base = beg;
    // 32-edge main loop: both chunks' gathers issued before any compute
    for (; base + 32 <= end; base += 32) {
        uint fuA[16], fuB[16];
        load_chunk16(Hf, dsts_sorted, base, l, fuA);
        load_chunk16(Hf, dsts_sorted, base + 16, l, fuB);
        compute_chunk16<true>(fuA, 16, l, hs2, av2, alpha2, acc0, acc1, rsp);
        compute_chunk16<true>(fuB, 16, l, hs2, av2, alpha2, acc0, acc1, rsp);
    }
    // 16-edge chunk
    if (base + 16 <= end) {
        uint fu[16];
        load_chunk16(Hf, dsts_sorted, base, l, fu);
        compute_chunk16<true>(fu, 16, l, hs2, av2, alpha2, acc0, acc1, rsp);
        base += 16;
    }
    // tail
    if (base < end) {
        int cnt = end - base;
        uint fu[16];
#pragma unroll
        for (int j = 0; j < 16; ++j) {
            int dj = dsts_sorted[base + (j < cnt ? j : 0)];
            const ushort* rp = Hf + ((size_t)(uint)dj << 7);
            fu[j] = *(const uint*)(rp + (l << 1));
        }
        compute_chunk16<false>(fu, cnt, l, hs2, av2, alpha2, acc0, acc1, rsp);
    }

    // rowsum: e replicated across 16-lane groups; fold within 16
    float rs = rsp;
    rs += __shfl_xor(rs, 1);
    rs += __shfl_xor(rs, 2);
    rs += __shfl_xor(rs, 4);
    rs += __shfl_xor(rs, 8);

    float inv = 1.0f / rs;
    float2 o;
    o.x = fmaxf(acc0 * inv, 0.f);
    o.y = fmaxf(acc1 * inv, 0.f);
    *(float2*)(out + ((size_t)node << 7) + (l << 1)) = o;
}

extern "C" void kernel_launch(void* const* d_in, const int* in_sizes, int n_in,
                              void* d_out, int out_size, void* d_ws, size_t ws_size,
                              hipStream_t stream) {
    const float* inputs = (const float*)d_in[0];
    const int* edge = (const int*)d_in[1];
    const float* W = (const float*)d_in[2];
    const float* a = (const float*)d_in[3];
    float* out = (float*)d_out;

    const int N = in_sizes[0] / D;   // 50000
    const int E = in_sizes[1] / 2;   // 800000

    const int* src = edge;
    const int* dst = edge + E;

    // ws layout
    ushort* wt = (ushort*)d_ws;                      // [16384] fp16
    ushort* hf = wt + 16384;                         // [N*128] fp16
    int* counts = (int*)(hf + (size_t)N * D);        // [N]
    int* starts = counts + N;                        // [N+1]
    int* rank = starts + N + 1;                      // [E]
    int* dsts_sorted = rank + E;                     // [E]

    const int nblk = (N + 255) / 256;                // 196
    const int eblk = (E + 255) / 256;                // 3125

    w_prep_kernel<<<64, 256, 0, stream>>>(W, wt);
    gemm_h_kernel<<<(N + 63) / 64, 256, 0, stream>>>(inputs, wt, hf, counts, N);
    hist_rank_kernel<<<eblk, 256, 0, stream>>>(src, counts, rank, E);
    scan_kernel<<<nblk, 256, 0, stream>>>(counts, starts, N);
    scatter_kernel<<<eblk, 256, 0, stream>>>(src, dst, rank, starts, dsts_sorted, E);
    node_kernel<<<N, 64, 0, stream>>>(hf, starts, dsts_sorted, a, out, N);
}

// Round 14
// 141.695 us; speedup vs baseline: 1.0409x; 1.0409x over previous
//
#include <hip/hip_runtime.h>
#include <cstdint>
#include <cstddef>

#define D 128
#define ALPHA 0.2f

typedef _Float16 half8_t __attribute__((ext_vector_type(8)));
typedef _Float16 v2h __attribute__((ext_vector_type(2)));
typedef __attribute__((ext_vector_type(4))) float f32x4_t;

static __device__ __forceinline__ ushort f2h(float f) {
    _Float16 h = (_Float16)f;
    return *(ushort*)&h;
}

static __device__ __forceinline__ float dot2f(v2h x, v2h y, float c) {
#if __has_builtin(__builtin_amdgcn_fdot2)
    return __builtin_amdgcn_fdot2(x, y, c, false);
#else
    return fmaf((float)x[0], (float)y[0], fmaf((float)x[1], (float)y[1], c));
#endif
}

// ---------------------------------------------------------------------------
// Kernel P: fused prep — counts[i]=0, Wt (transposed fp16), Ah (fp16 a)
// ---------------------------------------------------------------------------
__global__ __launch_bounds__(256) void prep_kernel(const float* __restrict__ W,
                                                   const float* __restrict__ a,
                                                   ushort* __restrict__ Wt,
                                                   ushort* __restrict__ Ah,
                                                   int* __restrict__ counts, int N) {
    int idx = blockIdx.x * 256 + threadIdx.x;
    if (idx < 16384) {
        int k = idx >> 7;
        int n = idx & 127;
        Wt[n * 128 + k] = f2h(W[idx]);
    }
    if (idx < 128) Ah[idx] = f2h(a[idx]);
    if (idx < N) counts[idx] = 0;
}

// ---------------------------------------------------------------------------
// Kernel 1: Hf = fp16(A @ W) via fp16 MFMA (fp32 accum).  [exact R12 version]
// ---------------------------------------------------------------------------
__global__ __launch_bounds__(256) void gemm_h_kernel(const float* __restrict__ A,
                                                     const ushort* __restrict__ Wt,
                                                     ushort* __restrict__ Hf,
                                                     int N) {
    __shared__ ushort Alds[64][136];
    const int tid = threadIdx.x;
    const int r0 = blockIdx.x * 64;

#pragma unroll
    for (int it = 0; it < 8; ++it) {
        int idx = it * 256 + tid;          // 0..2047
        int r = idx >> 5;
        int c4 = (idx & 31) * 4;
        float4 v = make_float4(0.f, 0.f, 0.f, 0.f);
        if (r0 + r < N) v = *(const float4*)(A + (size_t)(r0 + r) * D + c4);
        ushort4 b;
        b.x = f2h(v.x); b.y = f2h(v.y); b.z = f2h(v.z); b.w = f2h(v.w);
        *(ushort4*)&Alds[r][c4] = b;
    }
    __syncthreads();

    const int lane = tid & 63;
    const int w = tid >> 6;
    const int wm = w >> 1;
    const int wn = w & 1;
    const int l15 = lane & 15;
    const int koff = (lane >> 4) * 8;

    f32x4_t acc[2][4];
#pragma unroll
    for (int mt = 0; mt < 2; ++mt)
#pragma unroll
        for (int nt = 0; nt < 4; ++nt) acc[mt][nt] = (f32x4_t){0.f, 0.f, 0.f, 0.f};

    const int arow = wm * 32 + l15;
#pragma unroll
    for (int kk = 0; kk < 4; ++kk) {
        half8_t am0 = *(const half8_t*)&Alds[arow][kk * 32 + koff];
        half8_t am1 = *(const half8_t*)&Alds[arow + 16][kk * 32 + koff];
        half8_t bn[4];
#pragma unroll
        for (int nt = 0; nt < 4; ++nt)
            bn[nt] = *(const half8_t*)(Wt + (size_t)(wn * 64 + nt * 16 + l15) * 128 + kk * 32 + koff);
#pragma unroll
        for (int nt = 0; nt < 4; ++nt) {
            acc[0][nt] = __builtin_amdgcn_mfma_f32_16x16x32_f16(am0, bn[nt], acc[0][nt], 0, 0, 0);
            acc[1][nt] = __builtin_amdgcn_mfma_f32_16x16x32_f16(am1, bn[nt], acc[1][nt], 0, 0, 0);
        }
    }

    const int crow = (lane >> 4) * 4;
#pragma unroll
    for (int mt = 0; mt < 2; ++mt)
#pragma unroll
        for (int nt = 0; nt < 4; ++nt)
#pragma unroll
            for (int r = 0; r < 4; ++r) {
                int row = r0 + wm * 32 + mt * 16 + crow + r;
                if (row < N)
                    Hf[(size_t)row * D + wn * 64 + nt * 16 + l15] = f2h(acc[mt][nt][r]);
            }
}

// ---------------------------------------------------------------------------
// XCD-sliced CSR build. Grid = 8*eblk; block b (group g=b&7, lands on XCD g)
// reads edge range (b>>3) but acts only on src in slice g. All atomics and
// scattered writes for a line stay in one XCD's L2 (no cross-XCD line
// ping-pong). Slicing is a perf heuristic only — correctness is independent
// of the block->XCD mapping.
// ---------------------------------------------------------------------------
__global__ __launch_bounds__(256) void hist8_kernel(const int* __restrict__ src,
                                                    int* __restrict__ counts,
                                                    int E, int N) {
    int b = blockIdx.x;
    int g = b & 7;
    int i = ((b >> 3) << 8) + threadIdx.x;
    if (i >= E) return;
    int s = src[i];
    int lo = (g * N) >> 3;
    int hi = ((g + 1) * N) >> 3;
    if (s >= lo && s < hi) atomicAdd(&counts[s], 1);
}

__global__ __launch_bounds__(256) void scan_partial_kernel(const int* __restrict__ counts,
                                                           int* __restrict__ blocksum, int N) {
    __shared__ int wsum[4];
    int tid = threadIdx.x;
    int i = blockIdx.x * 256 + tid;
    int x = (i < N) ? counts[i] : 0;
#pragma unroll
    for (int off = 32; off > 0; off >>= 1) x += __shfl_down(x, off);
    if ((tid & 63) == 0) wsum[tid >> 6] = x;
    __syncthreads();
    if (tid == 0) blocksum[blockIdx.x] = wsum[0] + wsum[1] + wsum[2] + wsum[3];
}

// final scan: block offset from blocksum (<=256 entries) inline; writes
// starts AND cursor (cursor is consumed by the atomic scatter).
__global__ __launch_bounds__(256) void scan_final_kernel(const int* __restrict__ counts,
                                                         const int* __restrict__ blocksum,
                                                         int* __restrict__ starts,
                                                         int* __restrict__ cursor,
                                                         int nblk, int N) {
    __shared__ int bsum[4];
    __shared__ int wsum[4];
    int tid = threadIdx.x;
    int lane = tid & 63, w = tid >> 6;

    int x0 = (tid < nblk && tid < (int)blockIdx.x) ? blocksum[tid] : 0;
#pragma unroll
    for (int off = 32; off > 0; off >>= 1) x0 += __shfl_down(x0, off);
    if (lane == 0) bsum[w] = x0;
    __syncthreads();
    int blkoff = bsum[0] + bsum[1] + bsum[2] + bsum[3];

    int i = blockIdx.x * 256 + tid;
    int c = (i < N) ? counts[i] : 0;
    int x = c;
#pragma unroll
    for (int off = 1; off < 64; off <<= 1) {
        int y = __shfl_up(x, off);
        if (lane >= off) x += y;
    }
    if (lane == 63) wsum[w] = x;
    __syncthreads();
    int woff = blkoff;
    for (int j = 0; j < w; ++j) woff += wsum[j];
    int pre = woff + x - c;
    if (i < N) {
        starts[i] = pre;
        cursor[i] = pre;
        if (i == N - 1) starts[N] = pre + c;
    }
}

__global__ __launch_bounds__(256) void scatter8_kernel(const int* __restrict__ src,
                                                       const int* __restrict__ dst,
                                                       int* __restrict__ cursor,
                                                       int* __restrict__ dsts_sorted,
                                                       int E, int N) {
    int b = blockIdx.x;
    int g = b & 7;
    int i = ((b >> 3) << 8) + threadIdx.x;
    if (i >= E) return;
    int s = src[i];
    int lo = (g * N) >> 3;
    int hi = ((g + 1) * N) >> 3;
    if (s >= lo && s < hi) {
        int pos = atomicAdd(&cursor[s], 1);   // XCD-local L2 atomic
        dsts_sorted[pos] = dst[i];            // XCD-local line
    }
}

// ---------------------------------------------------------------------------
// Node kernel: 1 block = 1 wave = 1 node.  [exact R12 version]
// ---------------------------------------------------------------------------
template <bool FULL>
__device__ __forceinline__ void process_chunk(const ushort* __restrict__ Hf,
                                              const int* __restrict__ dsts_sorted,
                                              int base, int cnt, int l,
                                              v2h hs2, v2h av2, v2h alpha2,
                                              float& acc0, float& acc1, float& rsp) {
    uint fu[16];
#pragma unroll
    for (int j = 0; j < 16; ++j) {
        int idx = FULL ? (base + j) : (base + (j < cnt ? j : 0));
        int dj = dsts_sorted[idx];                       // wave-uniform -> s_load
        const ushort* rp = Hf + ((size_t)(uint)dj << 7); // SGPR base
        fu[j] = *(const uint*)(rp + (l << 1));
    }
    float p[16];
#pragma unroll
    for (int j = 0; j < 16; ++j) {
        v2h hv = *(v2h*)&fu[j];
        v2h s = hs2 + hv;                                    // v_pk_add_f16
        s = __builtin_elementwise_max(s, s * alpha2);        // v_pk_mul + v_pk_max
        float pj = dot2f(s, av2, 0.0f);                      // v_dot2_f32_f16
        p[j] = (FULL || j < cnt) ? pj : -1e30f;
    }
    {
        bool hi = l & 1;
#pragma unroll
        for (int i = 0; i < 8; ++i) {
            float send = hi ? p[i] : p[i + 8];
            float recv = __shfl_xor(send, 1);
            p[i] = (hi ? p[i + 8] : p[i]) + recv;
        }
        hi = l & 2;
#pragma unroll
        for (int i = 0; i < 4; ++i) {
            float send = hi ? p[i] : p[i + 4];
            float recv = __shfl_xor(send, 2);
            p[i] = (hi ? p[i + 4] : p[i]) + recv;
        }
        hi = l & 4;
#pragma unroll
        for (int i = 0; i < 2; ++i) {
            float send = hi ? p[i] : p[i + 2];
            float recv = __shfl_xor(send, 4);
            p[i] = (hi ? p[i + 2] : p[i]) + recv;
        }
        hi = l & 8;
        {
            float send = hi ? p[0] : p[1];
            float recv = __shfl_xor(send, 8);
            p[0] = (hi ? p[1] : p[0]) + recv;
        }
        p[0] += __shfl_xor(p[0], 16);
        p[0] += __shfl_xor(p[0], 32);
    }
    float e = __expf(p[0]);      // lane l: e of edge brev4(l&15), replicated per 16 lanes
    rsp += e;                    // deferred rowsum fold

    const int brev[16] = {0, 8, 4, 12, 2, 10, 6, 14, 1, 9, 5, 13, 3, 11, 7, 15};
#pragma unroll
    for (int j = 0; j < 16; ++j) {
        float ej = __uint_as_float(
            (uint)__builtin_amdgcn_readlane((int)__float_as_uint(e), brev[j]));
        v2h hv = *(v2h*)&fu[j];
        acc0 = fmaf((float)hv[0], ej, acc0);   // v_fma_mix
        acc1 = fmaf((float)hv[1], ej, acc1);   // v_fma_mix
    }
}

__global__ __launch_bounds__(64) void node_kernel(const ushort* __restrict__ Hf,
                                                  const int* __restrict__ starts,
                                                  const int* __restrict__ dsts_sorted,
                                                  const ushort* __restrict__ Ah,
                                                  float* __restrict__ out, int N) {
    const int node = blockIdx.x;   // wave-uniform
    const int l = threadIdx.x;     // 0..63

    const int beg = starts[node];
    const int end = starts[node + 1];

    uint hu = *(const uint*)(Hf + ((size_t)node << 7) + (l << 1));
    v2h hs2 = *(v2h*)&hu;
    uint au = *(const uint*)(Ah + (l << 1));
    v2h av2 = *(v2h*)&au;
    const v2h alpha2 = {(_Float16)ALPHA, (_Float16)ALPHA};

    float acc0 = 0.f, acc1 = 0.f, rsp = 0.f;

    int base = beg;
    for (; base + 16 <= end; base += 16)
        process_chunk<true>(Hf, dsts_sorted, base, 16, l, hs2, av2, alpha2, acc0, acc1, rsp);
    if (base < end)
        process_chunk<false>(Hf, dsts_sorted, base, end - base, l, hs2, av2, alpha2, acc0, acc1, rsp);

    float rs = rsp;
    rs += __shfl_xor(rs, 1);
    rs += __shfl_xor(rs, 2);
    rs += __shfl_xor(rs, 4);
    rs += __shfl_xor(rs, 8);

    float inv = 1.0f / rs;
    float2 o;
    o.x = fmaxf(acc0 * inv, 0.f);
    o.y = fmaxf(acc1 * inv, 0.f);
    *(float2*)(out + ((size_t)node << 7) + (l << 1)) = o;
}

extern "C" void kernel_launch(void* const* d_in, const int* in_sizes, int n_in,
                              void* d_out, int out_size, void* d_ws, size_t ws_size,
                              hipStream_t stream) {
    const float* inputs = (const float*)d_in[0];
    const int* edge = (const int*)d_in[1];
    const float* W = (const float*)d_in[2];
    const float* a = (const float*)d_in[3];
    float* out = (float*)d_out;

    const int N = in_sizes[0] / D;   // 50000 (divisible by 8)
    const int E = in_sizes[1] / 2;   // 800000

    const int* src = edge;
    const int* dst = edge + E;

    // ws layout
    ushort* wt = (ushort*)d_ws;                      // [16384] fp16
    ushort* ah = wt + 16384;                         // [128]  fp16
    ushort* hf = ah + 128;                           // [N*128] fp16
    int* counts = (int*)(hf + (size_t)N * D);        // [N]
    int* starts = counts + N;                        // [N+1]
    int* cursor = starts + N + 1;                    // [N]
    int* blocksum = cursor + N;                      // [256]
    int* dsts_sorted = blocksum + 256;               // [E]

    const int nblk = (N + 255) / 256;                // 196
    const int eblk = (E + 255) / 256;                // 3125

    prep_kernel<<<nblk, 256, 0, stream>>>(W, a, wt, ah, counts, N);
    gemm_h_kernel<<<(N + 63) / 64, 256, 0, stream>>>(inputs, wt, hf, N);
    hist8_kernel<<<8 * eblk, 256, 0, stream>>>(src, counts, E, N);
    scan_partial_kernel<<<nblk, 256, 0, stream>>>(counts, blocksum, N);
    scan_final_kernel<<<nblk, 256, 0, stream>>>(counts, blocksum, starts, cursor, nblk, N);
    scatter8_kernel<<<8 * eblk, 256, 0, stream>>>(src, dst, cursor, dsts_sorted, E, N);
    node_kernel<<<N, 64, 0, stream>>>(hf, starts, dsts_sorted, ah, out, N);
}

// Round 15
// 128.941 us; speedup vs baseline: 1.1438x; 1.0989x over previous
//
#include <hip/hip_runtime.h>
#include <cstdint>
#include <cstddef>

#define D 128
#define ALPHA 0.2f

typedef _Float16 half8_t __attribute__((ext_vector_type(8)));
typedef _Float16 v2h __attribute__((ext_vector_type(2)));
typedef __attribute__((ext_vector_type(4))) float f32x4_t;

static __device__ __forceinline__ ushort f2h(float f) {
    _Float16 h = (_Float16)f;
    return *(ushort*)&h;
}

static __device__ __forceinline__ float dot2f(v2h x, v2h y, float c) {
#if __has_builtin(__builtin_amdgcn_fdot2)
    return __builtin_amdgcn_fdot2(x, y, c, false);
#else
    return fmaf((float)x[0], (float)y[0], fmaf((float)x[1], (float)y[1], c));
#endif
}

// ---------------------------------------------------------------------------
// Kernel P: fused prep — counts[i]=0, Wt (transposed fp16), Ah (fp16 a)
// ---------------------------------------------------------------------------
__global__ __launch_bounds__(256) void prep_kernel(const float* __restrict__ W,
                                                   const float* __restrict__ a,
                                                   ushort* __restrict__ Wt,
                                                   ushort* __restrict__ Ah,
                                                   int* __restrict__ counts, int N) {
    int idx = blockIdx.x * 256 + threadIdx.x;
    if (idx < 16384) {
        int k = idx >> 7;
        int n = idx & 127;
        Wt[n * 128 + k] = f2h(W[idx]);
    }
    if (idx < 128) Ah[idx] = f2h(a[idx]);
    if (idx < N) counts[idx] = 0;
}

// ---------------------------------------------------------------------------
// Kernel 1: Hf = fp16(A @ W) via fp16 MFMA (fp32 accum).  [R12-proven]
// ---------------------------------------------------------------------------
__global__ __launch_bounds__(256) void gemm_h_kernel(const float* __restrict__ A,
                                                     const ushort* __restrict__ Wt,
                                                     ushort* __restrict__ Hf,
                                                     int N) {
    __shared__ ushort Alds[64][136];
    const int tid = threadIdx.x;
    const int r0 = blockIdx.x * 64;

#pragma unroll
    for (int it = 0; it < 8; ++it) {
        int idx = it * 256 + tid;          // 0..2047
        int r = idx >> 5;
        int c4 = (idx & 31) * 4;
        float4 v = make_float4(0.f, 0.f, 0.f, 0.f);
        if (r0 + r < N) v = *(const float4*)(A + (size_t)(r0 + r) * D + c4);
        ushort4 b;
        b.x = f2h(v.x); b.y = f2h(v.y); b.z = f2h(v.z); b.w = f2h(v.w);
        *(ushort4*)&Alds[r][c4] = b;
    }
    __syncthreads();

    const int lane = tid & 63;
    const int w = tid >> 6;
    const int wm = w >> 1;
    const int wn = w & 1;
    const int l15 = lane & 15;
    const int koff = (lane >> 4) * 8;

    f32x4_t acc[2][4];
#pragma unroll
    for (int mt = 0; mt < 2; ++mt)
#pragma unroll
        for (int nt = 0; nt < 4; ++nt) acc[mt][nt] = (f32x4_t){0.f, 0.f, 0.f, 0.f};

    const int arow = wm * 32 + l15;
#pragma unroll
    for (int kk = 0; kk < 4; ++kk) {
        half8_t am0 = *(const half8_t*)&Alds[arow][kk * 32 + koff];
        half8_t am1 = *(const half8_t*)&Alds[arow + 16][kk * 32 + koff];
        half8_t bn[4];
#pragma unroll
        for (int nt = 0; nt < 4; ++nt)
            bn[nt] = *(const half8_t*)(Wt + (size_t)(wn * 64 + nt * 16 + l15) * 128 + kk * 32 + koff);
#pragma unroll
        for (int nt = 0; nt < 4; ++nt) {
            acc[0][nt] = __builtin_amdgcn_mfma_f32_16x16x32_f16(am0, bn[nt], acc[0][nt], 0, 0, 0);
            acc[1][nt] = __builtin_amdgcn_mfma_f32_16x16x32_f16(am1, bn[nt], acc[1][nt], 0, 0, 0);
        }
    }

    const int crow = (lane >> 4) * 4;
#pragma unroll
    for (int mt = 0; mt < 2; ++mt)
#pragma unroll
        for (int nt = 0; nt < 4; ++nt)
#pragma unroll
            for (int r = 0; r < 4; ++r) {
                int row = r0 + wm * 32 + mt * 16 + crow + r;
                if (row < N)
                    Hf[(size_t)row * D + wn * 64 + nt * 16 + l15] = f2h(acc[mt][nt][r]);
            }
}

// ---------------------------------------------------------------------------
// CSR construction: hist(+rank) -> partial sums -> final scan -> scatter.
// Streaming arrays (src/dst/rank/dsts_sorted) use non-temporal hints: they
// are read/written exactly once; keeps L2 ways for counts/starts/Hf.
// ---------------------------------------------------------------------------
__global__ __launch_bounds__(256) void hist_rank_kernel(const int* __restrict__ src,
                                                        int* __restrict__ counts,
                                                        int* __restrict__ rank, int E) {
    int i = blockIdx.x * 256 + threadIdx.x;
    if (i >= E) return;
    int s = __builtin_nontemporal_load(src + i);
    int r = atomicAdd(&counts[s], 1);
    __builtin_nontemporal_store(r, rank + i);
}

__global__ __launch_bounds__(256) void scan_partial_kernel(const int* __restrict__ counts,
                                                           int* __restrict__ blocksum, int N) {
    __shared__ int wsum[4];
    int tid = threadIdx.x;
    int i = blockIdx.x * 256 + tid;
    int x = (i < N) ? counts[i] : 0;
#pragma unroll
    for (int off = 32; off > 0; off >>= 1) x += __shfl_down(x, off);
    if ((tid & 63) == 0) wsum[tid >> 6] = x;
    __syncthreads();
    if (tid == 0) blocksum[blockIdx.x] = wsum[0] + wsum[1] + wsum[2] + wsum[3];
}

// final scan: block offset computed in-block from blocksum (<=256 entries)
__global__ __launch_bounds__(256) void scan_final_kernel(const int* __restrict__ counts,
                                                         const int* __restrict__ blocksum,
                                                         int* __restrict__ starts,
                                                         int nblk, int N) {
    __shared__ int bsum[4];
    __shared__ int wsum[4];
    int tid = threadIdx.x;
    int lane = tid & 63, w = tid >> 6;

    int x0 = (tid < nblk && tid < (int)blockIdx.x) ? blocksum[tid] : 0;
#pragma unroll
    for (int off = 32; off > 0; off >>= 1) x0 += __shfl_down(x0, off);
    if (lane == 0) bsum[w] = x0;
    __syncthreads();
    int blkoff = bsum[0] + bsum[1] + bsum[2] + bsum[3];

    int i = blockIdx.x * 256 + tid;
    int c = (i < N) ? counts[i] : 0;
    int x = c;
#pragma unroll
    for (int off = 1; off < 64; off <<= 1) {
        int y = __shfl_up(x, off);
        if (lane >= off) x += y;
    }
    if (lane == 63) wsum[w] = x;
    __syncthreads();
    int woff = blkoff;
    for (int j = 0; j < w; ++j) woff += wsum[j];
    int pre = woff + x - c;
    if (i < N) {
        starts[i] = pre;
        if (i == N - 1) starts[N] = pre + c;
    }
}

__global__ __launch_bounds__(256) void scatter_kernel(const int* __restrict__ src,
                                                      const int* __restrict__ dst,
                                                      const int* __restrict__ rank,
                                                      const int* __restrict__ starts,
                                                      int* __restrict__ dsts_sorted, int E) {
    int i = blockIdx.x * 256 + threadIdx.x;
    if (i >= E) return;
    int s = __builtin_nontemporal_load(src + i);
    int d = __builtin_nontemporal_load(dst + i);
    int r = __builtin_nontemporal_load(rank + i);
    int pos = starts[s] + r;
    __builtin_nontemporal_store(d, dsts_sorted + pos);
}

// ---------------------------------------------------------------------------
// Node kernel: 1 block = 1 wave = 1 node (node = blockIdx.x wave-uniform ->
// scalar edge loads, SGPR gather base). fp16 packed QK (v_pk_add/mul/max +
// v_dot2_f32_f16); butterfly multi-reduce; readlane e-broadcast; deferred
// rowsum fold.  [R12-proven]
// ---------------------------------------------------------------------------
template <bool FULL>
__device__ __forceinline__ void process_chunk(const ushort* __restrict__ Hf,
                                              const int* __restrict__ dsts_sorted,
                                              int base, int cnt, int l,
                                              v2h hs2, v2h av2, v2h alpha2,
                                              float& acc0, float& acc1, float& rsp) {
    uint fu[16];
#pragma unroll
    for (int j = 0; j < 16; ++j) {
        int idx = FULL ? (base + j) : (base + (j < cnt ? j : 0));
        int dj = dsts_sorted[idx];                       // wave-uniform -> s_load
        const ushort* rp = Hf + ((size_t)(uint)dj << 7); // SGPR base
        fu[j] = *(const uint*)(rp + (l << 1));
    }
    float p[16];
#pragma unroll
    for (int j = 0; j < 16; ++j) {
        v2h hv = *(v2h*)&fu[j];
        v2h s = hs2 + hv;                                    // v_pk_add_f16
        s = __builtin_elementwise_max(s, s * alpha2);        // v_pk_mul + v_pk_max
        float pj = dot2f(s, av2, 0.0f);                      // v_dot2_f32_f16
        p[j] = (FULL || j < cnt) ? pj : -1e30f;
    }
    // butterfly multi-reduce: 16 values over 64 lanes
    {
        bool hi = l & 1;
#pragma unroll
        for (int i = 0; i < 8; ++i) {
            float send = hi ? p[i] : p[i + 8];
            float recv = __shfl_xor(send, 1);
            p[i] = (hi ? p[i + 8] : p[i]) + recv;
        }
        hi = l & 2;
#pragma unroll
        for (int i = 0; i < 4; ++i) {
            float send = hi ? p[i] : p[i + 4];
            float recv = __shfl_xor(send, 2);
            p[i] = (hi ? p[i + 4] : p[i]) + recv;
        }
        hi = l & 4;
#pragma unroll
        for (int i = 0; i < 2; ++i) {
            float send = hi ? p[i] : p[i + 2];
            float recv = __shfl_xor(send, 4);
            p[i] = (hi ? p[i + 2] : p[i]) + recv;
        }
        hi = l & 8;
        {
            float send = hi ? p[0] : p[1];
            float recv = __shfl_xor(send, 8);
            p[0] = (hi ? p[1] : p[0]) + recv;
        }
        p[0] += __shfl_xor(p[0], 16);
        p[0] += __shfl_xor(p[0], 32);
    }
    float e = __expf(p[0]);      // lane l: e of edge brev4(l&15), replicated per 16 lanes
    rsp += e;                    // deferred rowsum fold

    const int brev[16] = {0, 8, 4, 12, 2, 10, 6, 14, 1, 9, 5, 13, 3, 11, 7, 15};
#pragma unroll
    for (int j = 0; j < 16; ++j) {
        float ej = __uint_as_float(
            (uint)__builtin_amdgcn_readlane((int)__float_as_uint(e), brev[j]));
        v2h hv = *(v2h*)&fu[j];
        acc0 = fmaf((float)hv[0], ej, acc0);   // v_fma_mix
        acc1 = fmaf((float)hv[1], ej, acc1);   // v_fma_mix
    }
}

__global__ __launch_bounds__(64) void node_kernel(const ushort* __restrict__ Hf,
                                                  const int* __restrict__ starts,
                                                  const int* __restrict__ dsts_sorted,
                                                  const ushort* __restrict__ Ah,
                                                  float* __restrict__ out, int N) {
    const int node = blockIdx.x;   // wave-uniform
    const int l = threadIdx.x;     // 0..63

    const int beg = starts[node];
    const int end = starts[node + 1];

    uint hu = *(const uint*)(Hf + ((size_t)node << 7) + (l << 1));
    v2h hs2 = *(v2h*)&hu;
    uint au = *(const uint*)(Ah + (l << 1));
    v2h av2 = *(v2h*)&au;
    const v2h alpha2 = {(_Float16)ALPHA, (_Float16)ALPHA};

    float acc0 = 0.f, acc1 = 0.f, rsp = 0.f;

    int base = beg;
    for (; base + 16 <= end; base += 16)
        process_chunk<true>(Hf, dsts_sorted, base, 16, l, hs2, av2, alpha2, acc0, acc1, rsp);
    if (base < end)
        process_chunk<false>(Hf, dsts_sorted, base, end - base, l, hs2, av2, alpha2, acc0, acc1, rsp);

    // rowsum: e replicated across 16-lane groups; fold within 16
    float rs = rsp;
    rs += __shfl_xor(rs, 1);
    rs += __shfl_xor(rs, 2);
    rs += __shfl_xor(rs, 4);
    rs += __shfl_xor(rs, 8);

    float inv = 1.0f / rs;
    float2 o;
    o.x = fmaxf(acc0 * inv, 0.f);
    o.y = fmaxf(acc1 * inv, 0.f);
    *(float2*)(out + ((size_t)node << 7) + (l << 1)) = o;
}

extern "C" void kernel_launch(void* const* d_in, const int* in_sizes, int n_in,
                              void* d_out, int out_size, void* d_ws, size_t ws_size,
                              hipStream_t stream) {
    const float* inputs = (const float*)d_in[0];
    const int* edge = (const int*)d_in[1];
    const float* W = (const float*)d_in[2];
    const float* a = (const float*)d_in[3];
    float* out = (float*)d_out;

    const int N = in_sizes[0] / D;   // 50000
    const int E = in_sizes[1] / 2;   // 800000

    const int* src = edge;
    const int* dst = edge + E;

    // ws layout
    ushort* wt = (ushort*)d_ws;                      // [16384] fp16
    ushort* ah = wt + 16384;                         // [128]  fp16
    ushort* hf = ah + 128;                           // [N*128] fp16
    int* counts = (int*)(hf + (size_t)N * D);        // [N]
    int* starts = counts + N;                        // [N+1]
    int* blocksum = starts + N + 1;                  // [256]
    int* rank = blocksum + 256;                      // [E]
    int* dsts_sorted = rank + E;                     // [E]

    const int nblk = (N + 255) / 256;                // 196
    const int eblk = (E + 255) / 256;                // 3125

    prep_kernel<<<nblk, 256, 0, stream>>>(W, a, wt, ah, counts, N);
    gemm_h_kernel<<<(N + 63) / 64, 256, 0, stream>>>(inputs, wt, hf, N);
    hist_rank_kernel<<<eblk, 256, 0, stream>>>(src, counts, rank, E);
    scan_partial_kernel<<<nblk, 256, 0, stream>>>(counts, blocksum, N);
    scan_final_kernel<<<nblk, 256, 0, stream>>>(counts, blocksum, starts, nblk, N);
    scatter_kernel<<<eblk, 256, 0, stream>>>(src, dst, rank, starts, dsts_sorted, E);
    node_kernel<<<N, 64, 0, stream>>>(hf, starts, dsts_sorted, ah, out, N);
}

// Round 16
// 116.585 us; speedup vs baseline: 1.2650x; 1.1060x over previous
//
#include <hip/hip_runtime.h>
#include <cstdint>
#include <cstddef>

#define D 128
#define ALPHA 0.2f

typedef _Float16 half8_t __attribute__((ext_vector_type(8)));
typedef _Float16 v2h __attribute__((ext_vector_type(2)));
typedef __attribute__((ext_vector_type(4))) float f32x4_t;

static __device__ __forceinline__ ushort f2h(float f) {
    _Float16 h = (_Float16)f;
    return *(ushort*)&h;
}

static __device__ __forceinline__ float dot2f(v2h x, v2h y, float c) {
#if __has_builtin(__builtin_amdgcn_fdot2)
    return __builtin_amdgcn_fdot2(x, y, c, false);
#else
    return fmaf((float)x[0], (float)y[0], fmaf((float)x[1], (float)y[1], c));
#endif
}

// ---------------------------------------------------------------------------
// Kernel P: fused prep — counts[i]=0, Wt (transposed fp16), Ah (fp16 a)
// ---------------------------------------------------------------------------
__global__ __launch_bounds__(256) void prep_kernel(const float* __restrict__ W,
                                                   const float* __restrict__ a,
                                                   ushort* __restrict__ Wt,
                                                   ushort* __restrict__ Ah,
                                                   int* __restrict__ counts, int N) {
    int idx = blockIdx.x * 256 + threadIdx.x;
    if (idx < 16384) {
        int k = idx >> 7;
        int n = idx & 127;
        Wt[n * 128 + k] = f2h(W[idx]);
    }
    if (idx < 128) Ah[idx] = f2h(a[idx]);
    if (idx < N) counts[idx] = 0;
}

// ---------------------------------------------------------------------------
// Kernel 1: Hf = fp16(A @ W) via fp16 MFMA (fp32 accum).  [R12-proven]
// ---------------------------------------------------------------------------
__global__ __launch_bounds__(256) void gemm_h_kernel(const float* __restrict__ A,
                                                     const ushort* __restrict__ Wt,
                                                     ushort* __restrict__ Hf,
                                                     int N) {
    __shared__ ushort Alds[64][136];
    const int tid = threadIdx.x;
    const int r0 = blockIdx.x * 64;

#pragma unroll
    for (int it = 0; it < 8; ++it) {
        int idx = it * 256 + tid;          // 0..2047
        int r = idx >> 5;
        int c4 = (idx & 31) * 4;
        float4 v = make_float4(0.f, 0.f, 0.f, 0.f);
        if (r0 + r < N) v = *(const float4*)(A + (size_t)(r0 + r) * D + c4);
        ushort4 b;
        b.x = f2h(v.x); b.y = f2h(v.y); b.z = f2h(v.z); b.w = f2h(v.w);
        *(ushort4*)&Alds[r][c4] = b;
    }
    __syncthreads();

    const int lane = tid & 63;
    const int w = tid >> 6;
    const int wm = w >> 1;
    const int wn = w & 1;
    const int l15 = lane & 15;
    const int koff = (lane >> 4) * 8;

    f32x4_t acc[2][4];
#pragma unroll
    for (int mt = 0; mt < 2; ++mt)
#pragma unroll
        for (int nt = 0; nt < 4; ++nt) acc[mt][nt] = (f32x4_t){0.f, 0.f, 0.f, 0.f};

    const int arow = wm * 32 + l15;
#pragma unroll
    for (int kk = 0; kk < 4; ++kk) {
        half8_t am0 = *(const half8_t*)&Alds[arow][kk * 32 + koff];
        half8_t am1 = *(const half8_t*)&Alds[arow + 16][kk * 32 + koff];
        half8_t bn[4];
#pragma unroll
        for (int nt = 0; nt < 4; ++nt)
            bn[nt] = *(const half8_t*)(Wt + (size_t)(wn * 64 + nt * 16 + l15) * 128 + kk * 32 + koff);
#pragma unroll
        for (int nt = 0; nt < 4; ++nt) {
            acc[0][nt] = __builtin_amdgcn_mfma_f32_16x16x32_f16(am0, bn[nt], acc[0][nt], 0, 0, 0);
            acc[1][nt] = __builtin_amdgcn_mfma_f32_16x16x32_f16(am1, bn[nt], acc[1][nt], 0, 0, 0);
        }
    }

    const int crow = (lane >> 4) * 4;
#pragma unroll
    for (int mt = 0; mt < 2; ++mt)
#pragma unroll
        for (int nt = 0; nt < 4; ++nt)
#pragma unroll
            for (int r = 0; r < 4; ++r) {
                int row = r0 + wm * 32 + mt * 16 + crow + r;
                if (row < N)
                    Hf[(size_t)row * D + wn * 64 + nt * 16 + l15] = f2h(acc[mt][nt][r]);
            }
}

// ---------------------------------------------------------------------------
// CSR construction: hist(+rank) -> partial sums -> final scan -> scatter.
// (plain loads/stores — R15 showed nt hints break producer->consumer reuse)
// ---------------------------------------------------------------------------
__global__ __launch_bounds__(256) void hist_rank_kernel(const int* __restrict__ src,
                                                        int* __restrict__ counts,
                                                        int* __restrict__ rank, int E) {
    int i = blockIdx.x * 256 + threadIdx.x;
    if (i >= E) return;
    rank[i] = atomicAdd(&counts[src[i]], 1);
}

__global__ __launch_bounds__(256) void scan_partial_kernel(const int* __restrict__ counts,
                                                           int* __restrict__ blocksum, int N) {
    __shared__ int wsum[4];
    int tid = threadIdx.x;
    int i = blockIdx.x * 256 + tid;
    int x = (i < N) ? counts[i] : 0;
#pragma unroll
    for (int off = 32; off > 0; off >>= 1) x += __shfl_down(x, off);
    if ((tid & 63) == 0) wsum[tid >> 6] = x;
    __syncthreads();
    if (tid == 0) blocksum[blockIdx.x] = wsum[0] + wsum[1] + wsum[2] + wsum[3];
}

// final scan: block offset computed in-block from blocksum (<=256 entries)
__global__ __launch_bounds__(256) void scan_final_kernel(const int* __restrict__ counts,
                                                         const int* __restrict__ blocksum,
                                                         int* __restrict__ starts,
                                                         int nblk, int N) {
    __shared__ int bsum[4];
    __shared__ int wsum[4];
    int tid = threadIdx.x;
    int lane = tid & 63, w = tid >> 6;

    int x0 = (tid < nblk && tid < (int)blockIdx.x) ? blocksum[tid] : 0;
#pragma unroll
    for (int off = 32; off > 0; off >>= 1) x0 += __shfl_down(x0, off);
    if (lane == 0) bsum[w] = x0;
    __syncthreads();
    int blkoff = bsum[0] + bsum[1] + bsum[2] + bsum[3];

    int i = blockIdx.x * 256 + tid;
    int c = (i < N) ? counts[i] : 0;
    int x = c;
#pragma unroll
    for (int off = 1; off < 64; off <<= 1) {
        int y = __shfl_up(x, off);
        if (lane >= off) x += y;
    }
    if (lane == 63) wsum[w] = x;
    __syncthreads();
    int woff = blkoff;
    for (int j = 0; j < w; ++j) woff += wsum[j];
    int pre = woff + x - c;
    if (i < N) {
        starts[i] = pre;
        if (i == N - 1) starts[N] = pre + c;
    }
}

// dsts_sorted stored as ushort (dst < 50000 < 65536): halves scattered-store
// line footprint and node_kernel's edge-list bytes.
__global__ __launch_bounds__(256) void scatter_kernel(const int* __restrict__ src,
                                                      const int* __restrict__ dst,
                                                      const int* __restrict__ rank,
                                                      const int* __restrict__ starts,
                                                      ushort* __restrict__ dsts_sorted, int E) {
    int i = blockIdx.x * 256 + threadIdx.x;
    if (i >= E) return;
    int pos = starts[src[i]] + rank[i];
    dsts_sorted[pos] = (ushort)dst[i];
}

// ---------------------------------------------------------------------------
// Node kernel: 1 block = 1 wave = 1 node (node = blockIdx.x wave-uniform ->
// scalar edge loads, SGPR gather base). fp16 packed QK (v_pk_add/mul/max +
// v_dot2_f32_f16); butterfly multi-reduce; readlane e-broadcast; deferred
// rowsum fold.  [R12-proven; edge list now ushort]
// ---------------------------------------------------------------------------
template <bool FULL>
__device__ __forceinline__ void process_chunk(const ushort* __restrict__ Hf,
                                              const ushort* __restrict__ dsts_sorted,
                                              int base, int cnt, int l,
                                              v2h hs2, v2h av2, v2h alpha2,
                                              float& acc0, float& acc1, float& rsp) {
    uint fu[16];
#pragma unroll
    for (int j = 0; j < 16; ++j) {
        int idx = FULL ? (base + j) : (base + (j < cnt ? j : 0));
        uint dj = dsts_sorted[idx];                      // wave-uniform -> s_load
        const ushort* rp = Hf + ((size_t)dj << 7);       // SGPR base
        fu[j] = *(const uint*)(rp + (l << 1));
    }
    float p[16];
#pragma unroll
    for (int j = 0; j < 16; ++j) {
        v2h hv = *(v2h*)&fu[j];
        v2h s = hs2 + hv;                                    // v_pk_add_f16
        s = __builtin_elementwise_max(s, s * alpha2);        // v_pk_mul + v_pk_max
        float pj = dot2f(s, av2, 0.0f);                      // v_dot2_f32_f16
        p[j] = (FULL || j < cnt) ? pj : -1e30f;
    }
    // butterfly multi-reduce: 16 values over 64 lanes
    {
        bool hi = l & 1;
#pragma unroll
        for (int i = 0; i < 8; ++i) {
            float send = hi ? p[i] : p[i + 8];
            float recv = __shfl_xor(send, 1);
            p[i] = (hi ? p[i + 8] : p[i]) + recv;
        }
        hi = l & 2;
#pragma unroll
        for (int i = 0; i < 4; ++i) {
            float send = hi ? p[i] : p[i + 4];
            float recv = __shfl_xor(send, 2);
            p[i] = (hi ? p[i + 4] : p[i]) + recv;
        }
        hi = l & 4;
#pragma unroll
        for (int i = 0; i < 2; ++i) {
            float send = hi ? p[i] : p[i + 2];
            float recv = __shfl_xor(send, 4);
            p[i] = (hi ? p[i + 2] : p[i]) + recv;
        }
        hi = l & 8;
        {
            float send = hi ? p[0] : p[1];
            float recv = __shfl_xor(send, 8);
            p[0] = (hi ? p[1] : p[0]) + recv;
        }
        p[0] += __shfl_xor(p[0], 16);
        p[0] += __shfl_xor(p[0], 32);
    }
    float e = __expf(p[0]);      // lane l: e of edge brev4(l&15), replicated per 16 lanes
    rsp += e;                    // deferred rowsum fold

    const int brev[16] = {0, 8, 4, 12, 2, 10, 6, 14, 1, 9, 5, 13, 3, 11, 7, 15};
#pragma unroll
    for (int j = 0; j < 16; ++j) {
        float ej = __uint_as_float(
            (uint)__builtin_amdgcn_readlane((int)__float_as_uint(e), brev[j]));
        v2h hv = *(v2h*)&fu[j];
        acc0 = fmaf((float)hv[0], ej, acc0);   // v_fma_mix
        acc1 = fmaf((float)hv[1], ej, acc1);   // v_fma_mix
    }
}

__global__ __launch_bounds__(64) void node_kernel(const ushort* __restrict__ Hf,
                                                  const int* __restrict__ starts,
                                                  const ushort* __restrict__ dsts_sorted,
                                                  const ushort* __restrict__ Ah,
                                                  float* __restrict__ out, int N) {
    const int node = blockIdx.x;   // wave-uniform
    const int l = threadIdx.x;     // 0..63

    const int beg = starts[node];
    const int end = starts[node + 1];

    uint hu = *(const uint*)(Hf + ((size_t)node << 7) + (l << 1));
    v2h hs2 = *(v2h*)&hu;
    uint au = *(const uint*)(Ah + (l << 1));
    v2h av2 = *(v2h*)&au;
    const v2h alpha2 = {(_Float16)ALPHA, (_Float16)ALPHA};

    float acc0 = 0.f, acc1 = 0.f, rsp = 0.f;

    int base = beg;
    for (; base + 16 <= end; base += 16)
        process_chunk<true>(Hf, dsts_sorted, base, 16, l, hs2, av2, alpha2, acc0, acc1, rsp);
    if (base < end)
        process_chunk<false>(Hf, dsts_sorted, base, end - base, l, hs2, av2, alpha2, acc0, acc1, rsp);

    // rowsum: e replicated across 16-lane groups; fold within 16
    float rs = rsp;
    rs += __shfl_xor(rs, 1);
    rs += __shfl_xor(rs, 2);
    rs += __shfl_xor(rs, 4);
    rs += __shfl_xor(rs, 8);

    float inv = 1.0f / rs;
    float2 o;
    o.x = fmaxf(acc0 * inv, 0.f);
    o.y = fmaxf(acc1 * inv, 0.f);
    *(float2*)(out + ((size_t)node << 7) + (l << 1)) = o;
}

extern "C" void kernel_launch(void* const* d_in, const int* in_sizes, int n_in,
                              void* d_out, int out_size, void* d_ws, size_t ws_size,
                              hipStream_t stream) {
    const float* inputs = (const float*)d_in[0];
    const int* edge = (const int*)d_in[1];
    const float* W = (const float*)d_in[2];
    const float* a = (const float*)d_in[3];
    float* out = (float*)d_out;

    const int N = in_sizes[0] / D;   // 50000
    const int E = in_sizes[1] / 2;   // 800000

    const int* src = edge;
    const int* dst = edge + E;

    // ws layout
    ushort* wt = (ushort*)d_ws;                      // [16384] fp16
    ushort* ah = wt + 16384;                         // [128]  fp16
    ushort* hf = ah + 128;                           // [N*128] fp16
    int* counts = (int*)(hf + (size_t)N * D);        // [N]
    int* starts = counts + N;                        // [N+1]
    int* blocksum = starts + N + 1;                  // [256]
    int* rank = blocksum + 256;                      // [E]
    ushort* dsts_sorted = (ushort*)(rank + E);       // [E] ushort

    const int nblk = (N + 255) / 256;                // 196
    const int eblk = (E + 255) / 256;                // 3125

    prep_kernel<<<nblk, 256, 0, stream>>>(W, a, wt, ah, counts, N);
    gemm_h_kernel<<<(N + 63) / 64, 256, 0, stream>>>(inputs, wt, hf, N);
    hist_rank_kernel<<<eblk, 256, 0, stream>>>(src, counts, rank, E);
    scan_partial_kernel<<<nblk, 256, 0, stream>>>(counts, blocksum, N);
    scan_final_kernel<<<nblk, 256, 0, stream>>>(counts, blocksum, starts, nblk, N);
    scatter_kernel<<<eblk, 256, 0, stream>>>(src, dst, rank, starts, dsts_sorted, E);
    node_kernel<<<N, 64, 0, stream>>>(hf, starts, dsts_sorted, ah, out, N);
}